// Round 8
// baseline (13689.622 us; speedup 1.0000x reference)
//
#include <hip/hip_runtime.h>
#include <hip/hip_bf16.h>

// ---------------------------------------------------------------------------
// LSTMTagger: char-LSTM (batched, MFMA) -> word-LSTM (sequential, 16-WG
// push-mailbox pipeline: producers push h into each consumer's PRIVATE
// double-buffered mailbox; consumers poll only their own lines) -> tag
// projection + log_softmax(axis=0). Float I/O f32; bf16 only in MFMA stages.
// Hand-rolled sc0 is BANNED (falsified R3/R6). No intra-wave poller deps
// (R7 timeout lesson). All spins guarded -> fail loud, never hang.
// ---------------------------------------------------------------------------

typedef short short8 __attribute__((ext_vector_type(8)));   // 8 bf16 (4 VGPRs)
typedef float f32x4 __attribute__((ext_vector_type(4)));    // MFMA acc

#define NUM_S 4096
#define NUM_L 16

__device__ __forceinline__ unsigned short f2bf(float f) {  // RTNE
  unsigned x = __float_as_uint(f);
  x += 0x7FFFu + ((x >> 16) & 1u);
  return (unsigned short)(x >> 16);
}
__device__ __forceinline__ uint4 packf8(float4 a, float4 b) {  // 8 f32 -> 8 bf16
  uint4 r;
  r.x = (unsigned)f2bf(a.x) | ((unsigned)f2bf(a.y) << 16);
  r.y = (unsigned)f2bf(a.z) | ((unsigned)f2bf(a.w) << 16);
  r.z = (unsigned)f2bf(b.x) | ((unsigned)f2bf(b.y) << 16);
  r.w = (unsigned)f2bf(b.z) | ((unsigned)f2bf(b.w) << 16);
  return r;
}
__device__ __forceinline__ short8 pack_bf8(const float* src) {  // 16B-aligned
  const float4 a = *reinterpret_cast<const float4*>(src);
  const float4 b = *reinterpret_cast<const float4*>(src + 4);
  uint4 u = packf8(a, b);
  union { uint4 u; short8 s; } cv; cv.u = u;
  return cv.s;
}
__device__ __forceinline__ float sigm(float x) { return 1.0f / (1.0f + __expf(-x)); }
__device__ __forceinline__ float tanh_f(float x) {
  x = fminf(15.0f, fmaxf(-15.0f, x));
  float e = __expf(2.0f * x);
  return (e - 1.0f) / (e + 1.0f);
}

// ---------------------------------------------------------------------------
// Kernel A: char LSTM. One WG = 16 words, 256 threads (4 waves).
// Weights (Wih_c||Whh_c as 512x256) held as bf16 MFMA B-frags in VGPRs.
// ---------------------------------------------------------------------------
__global__ __launch_bounds__(256, 1) void char_lstm_kernel(
    const int* __restrict__ char_idxs,    // [S][L]
    const int* __restrict__ char_lens,    // [S]
    const float* __restrict__ char_emb,   // [128][128]
    const float* __restrict__ Wih_c,      // [512][128]
    const float* __restrict__ Whh_c,      // [512][128]
    const float* __restrict__ bih_c,      // [512]
    const float* __restrict__ bhh_c,      // [512]
    float* __restrict__ char_feat)        // [S][128]
{
  constexpr int XSTR = 264;  // 256 + 8 pad (bf16 elems)
  __shared__ __align__(16) unsigned short X[16 * XSTR];

  const int wg = blockIdx.x;
  const int tid = threadIdx.x;
  const int lane = tid & 63;
  const int wv = tid >> 6;
  const int col = lane & 15;
  const int krow = lane >> 4;

  short8 wfrag[8][8];
#pragma unroll
  for (int p = 0; p < 8; ++p) {
    const int nt = (p >> 1) * 8 + 2 * wv + (p & 1);
    const int n = nt * 16 + col;
#pragma unroll
    for (int kt = 0; kt < 8; ++kt) {
      const int k = kt * 32 + krow * 8;
      const float* src = (kt < 4) ? (Wih_c + n * 128 + k)
                                  : (Whh_c + n * 128 + (k - 128));
      wfrag[p][kt] = pack_bf8(src);
    }
  }
  float bsum[8];
#pragma unroll
  for (int p = 0; p < 8; ++p) {
    const int nt = (p >> 1) * 8 + 2 * wv + (p & 1);
    const int n = nt * 16 + col;
    bsum[p] = bih_c[n] + bhh_c[n];
  }
  int clen[4];
#pragma unroll
  for (int r = 0; r < 4; ++r) clen[r] = char_lens[wg * 16 + krow * 4 + r];

  {
    const int m = tid >> 4, c = tid & 15;
    uint4 z; z.x = z.y = z.z = z.w = 0u;
    *reinterpret_cast<uint4*>(&X[m * XSTR + 128 + c * 8]) = z;
  }
  float cstate[8];
#pragma unroll
  for (int i = 0; i < 8; ++i) cstate[i] = 0.0f;

  for (int l = 0; l < NUM_L; ++l) {
    {
      const int m = tid >> 4, c = tid & 15;
      const int ci = char_idxs[(wg * 16 + m) * NUM_L + l];
      const float4 a = *reinterpret_cast<const float4*>(char_emb + ci * 128 + c * 8);
      const float4 b = *reinterpret_cast<const float4*>(char_emb + ci * 128 + c * 8 + 4);
      *reinterpret_cast<uint4*>(&X[m * XSTR + c * 8]) = packf8(a, b);
    }
    __syncthreads();

    short8 afr[8];
#pragma unroll
    for (int kt = 0; kt < 8; ++kt)
      afr[kt] = *reinterpret_cast<const short8*>(&X[col * XSTR + kt * 32 + krow * 8]);

    f32x4 acc[8];
#pragma unroll
    for (int p = 0; p < 8; ++p) { f32x4 v = {bsum[p], bsum[p], bsum[p], bsum[p]}; acc[p] = v; }
#pragma unroll
    for (int kt = 0; kt < 8; ++kt)
#pragma unroll
      for (int p = 0; p < 8; ++p)
        acc[p] = __builtin_amdgcn_mfma_f32_16x16x32_bf16(afr[kt], wfrag[p][kt], acc[p], 0, 0, 0);
    __syncthreads();

#pragma unroll
    for (int sub = 0; sub < 2; ++sub) {
#pragma unroll
      for (int r = 0; r < 4; ++r) {
        const int m = krow * 4 + r;
        const int d = (2 * wv + sub) * 16 + col;
        const float iv = acc[0 + sub][r];
        const float fv = acc[2 + sub][r];
        const float gv = acc[4 + sub][r];
        const float ov = acc[6 + sub][r];
        const float cc = sigm(fv) * cstate[sub * 4 + r] + sigm(iv) * tanh_f(gv);
        const float hh = sigm(ov) * tanh_f(cc);
        cstate[sub * 4 + r] = cc;
        X[m * XSTR + 128 + d] = (unsigned short)f2bf(hh);
        if (clen[r] == l + 1) char_feat[(wg * 16 + m) * 128 + d] = hh;
      }
    }
  }
}

// ---------------------------------------------------------------------------
// Kernel W: convert Wih_w f32 -> bf16 workspace.
// ---------------------------------------------------------------------------
__global__ __launch_bounds__(256) void cvt_bf16_kernel(
    const float* __restrict__ in, unsigned short* __restrict__ out, int n8) {
  const int i = blockIdx.x * 256 + threadIdx.x;
  if (i < n8) {
    const float4 a = reinterpret_cast<const float4*>(in)[2 * i];
    const float4 b = reinterpret_cast<const float4*>(in)[2 * i + 1];
    reinterpret_cast<uint4*>(out)[i] = packf8(a, b);
  }
}

// ---------------------------------------------------------------------------
// Kernel B: xpart[t] = Wih_w @ [we[t] | char_feat[t]] + bih_w + bhh_w.
// ---------------------------------------------------------------------------
__global__ __launch_bounds__(256, 1) void word_input_kernel(
    const int* __restrict__ word_idxs,
    const float* __restrict__ word_emb,            // [V][256]
    const float* __restrict__ char_feat,           // [S][128]
    const unsigned short* __restrict__ wih_bf,     // [2048][384] bf16
    const float* __restrict__ bih_w,               // [2048]
    const float* __restrict__ bhh_w,               // [2048]
    float* __restrict__ xpart)                     // [S][2048]
{
  constexpr int XSTR = 392;  // 384 + 8 pad (bf16)
  __shared__ __align__(16) unsigned short X[64 * XSTR];
  const int wg = blockIdx.x, tid = threadIdx.x;
  const int lane = tid & 63, wv = tid >> 6, col = lane & 15, krow = lane >> 4;
  const int t0 = wg * 64;

#pragma unroll
  for (int rr = 0; rr < 4; ++rr) {
    const int m = rr * 16 + (tid >> 4), c = tid & 15;
    const int widx = word_idxs[t0 + m];
    const float* we = word_emb + (size_t)widx * 256;
    const float4 a0 = *reinterpret_cast<const float4*>(we + c * 8);
    const float4 b0 = *reinterpret_cast<const float4*>(we + c * 8 + 4);
    *reinterpret_cast<uint4*>(&X[m * XSTR + c * 8]) = packf8(a0, b0);
    const float4 a1 = *reinterpret_cast<const float4*>(we + 128 + c * 8);
    const float4 b1 = *reinterpret_cast<const float4*>(we + 128 + c * 8 + 4);
    *reinterpret_cast<uint4*>(&X[m * XSTR + 128 + c * 8]) = packf8(a1, b1);
    const float* cf = char_feat + (size_t)(t0 + m) * 128;
    const float4 a2 = *reinterpret_cast<const float4*>(cf + c * 8);
    const float4 b2 = *reinterpret_cast<const float4*>(cf + c * 8 + 4);
    *reinterpret_cast<uint4*>(&X[m * XSTR + 256 + c * 8]) = packf8(a2, b2);
  }
  __syncthreads();

  short8 afr[4][12];
#pragma unroll
  for (int mt = 0; mt < 4; ++mt)
#pragma unroll
    for (int kt = 0; kt < 12; ++kt)
      afr[mt][kt] = *reinterpret_cast<const short8*>(
          &X[(mt * 16 + col) * XSTR + kt * 32 + krow * 8]);

  for (int nn = 0; nn < 32; ++nn) {
    const int nt = wv * 32 + nn;
    const int n = nt * 16 + col;
    const float bs = bih_w[n] + bhh_w[n];
    f32x4 acc[4];
#pragma unroll
    for (int mt = 0; mt < 4; ++mt) { f32x4 v = {bs, bs, bs, bs}; acc[mt] = v; }
#pragma unroll
    for (int kt = 0; kt < 12; ++kt) {
      const short8 bfr = *reinterpret_cast<const short8*>(
          wih_bf + (size_t)n * 384 + kt * 32 + krow * 8);
#pragma unroll
      for (int mt = 0; mt < 4; ++mt)
        acc[mt] = __builtin_amdgcn_mfma_f32_16x16x32_bf16(afr[mt][kt], bfr, acc[mt], 0, 0, 0);
    }
#pragma unroll
    for (int mt = 0; mt < 4; ++mt)
#pragma unroll
      for (int r = 0; r < 4; ++r)
        xpart[(size_t)(t0 + mt * 16 + krow * 4 + r) * 2048 + n] = acc[mt][r];
  }
}

// ---------------------------------------------------------------------------
// Kernel C: sequential word LSTM. 16 WGs x 512 thr, R5's proven skeleton +
// push-mailboxes. tid = dim(5b)|gate(2b)|seg(2b); quarter-row of Whh in
// VGPRs (seg-rotated -> conflict-free LDS h reads). Per step:
//   A) FMA + shfl seg-reduce; seg0 adds xpart, writes glds. bar1.
//   B) leaders (tid<32): nonlinearity (c in reg); wout store (plain);
//      h_lds[nxt] own dims; __threadfence(); push flag-encoded h
//      (bits(h)+0x40000000) to the 15 OTHER WGs' private mailboxes
//      mbox[c][t&1][wg*32+dim] (relaxed dword stores, fire-and-forget).
//      Pollers (tid>=256, chunk k=tid-256, skip own 16): acquire-poll u64
//      of OWN mailbox (private lines, <=16 pollers/line, no cross-WG line
//      sharing), clear to 0 for parity reuse at t+2, decode to h_lds[nxt].
//      bar2. No intra-wave dependencies; all spins guarded (fail loud).
// ---------------------------------------------------------------------------
__global__ __launch_bounds__(512, 1) void word_lstm_kernel(
    const float* __restrict__ Whh_w,   // [2048][512] f32
    const float* __restrict__ xpart,   // [S][2048]
    float* __restrict__ wout,          // [S][512] plain f32
    unsigned* __restrict__ mbox)       // [16][2][512] flag-encoded, zeroed
{
  const int tid = threadIdx.x;
  const int wg = blockIdx.x;           // 16 WGs
  const int dim = tid >> 4;            // 0..31
  const int gate = (tid >> 2) & 3;     // i,f,g,o
  const int seg = tid & 3;             // K quarter
  const int R = gate * 512 + wg * 32 + dim;

  // quarter-row of Whh, pre-rotated by seg (compile-time reg indices; LDS
  // chunk order differs per seg -> no 4-way bank conflict on h reads)
  float4 w4[32];
  {
    const float4* wrow = reinterpret_cast<const float4*>(
        Whh_w + (size_t)R * 512 + seg * 128);
#pragma unroll
    for (int i = 0; i < 32; ++i) w4[i] = wrow[(i + seg) & 31];
  }

  __shared__ __align__(16) float h_lds[2][512];
  __shared__ float glds[128];
  h_lds[0][tid] = 0.0f;
  float creg = 0.0f;
  float xp = (seg == 0) ? xpart[R] : 0.0f;  // t=0 prefetch
  __syncthreads();

  for (int t = 0; t < NUM_S; ++t) {
    const int cur = t & 1, nxt = cur ^ 1, par = t & 1;

    // ---- phase A: gates = Whh @ h (2-way split chains) ----
    const float4* h4 = reinterpret_cast<const float4*>(&h_lds[cur][0]) + seg * 32;
    float a0 = 0.0f, a1 = 0.0f;
#pragma unroll
    for (int jj = 0; jj < 32; jj += 2) {
      const int j0 = (jj + seg) & 31;
      const int j1 = (jj + 1 + seg) & 31;
      const float4 hA = h4[j0]; const float4 wA = w4[jj];
      const float4 hB = h4[j1]; const float4 wB = w4[jj + 1];
      a0 = fmaf(wA.x, hA.x, a0); a0 = fmaf(wA.y, hA.y, a0);
      a0 = fmaf(wA.z, hA.z, a0); a0 = fmaf(wA.w, hA.w, a0);
      a1 = fmaf(wB.x, hB.x, a1); a1 = fmaf(wB.y, hB.y, a1);
      a1 = fmaf(wB.z, hB.z, a1); a1 = fmaf(wB.w, hB.w, a1);
    }
    float acc = a0 + a1;
    acc += __shfl_xor(acc, 1, 64);
    acc += __shfl_xor(acc, 2, 64);
    if (seg == 0) {
      glds[gate * 32 + dim] = acc + xp;
      if (t + 1 < NUM_S) xp = xpart[(size_t)(t + 1) * 2048 + R];  // prefetch
    }
    __syncthreads();  // bar 1: gates visible

    // ---- phase B: leaders nonlinearity + mailbox push ----
    if (tid < 32) {
      const float iv = glds[tid];
      const float fv = glds[32 + tid];
      const float gv = glds[64 + tid];
      const float ov = glds[96 + tid];
      const float cc = sigm(fv) * creg + sigm(iv) * tanh_f(gv);
      const float hh = sigm(ov) * tanh_f(cc);
      creg = cc;
      wout[(size_t)t * 512 + wg * 32 + tid] = hh;
      h_lds[nxt][wg * 32 + tid] = hh;  // own dims: no mailbox round-trip
      if (t + 1 < NUM_S) {
        const unsigned fb = __float_as_uint(hh) + 0x40000000u;
        __threadfence();  // publish prior (incl. barrier-ordered clears)
#pragma unroll
        for (int c = 0; c < 16; ++c) {
          if (c != wg)
            __hip_atomic_store(mbox + ((size_t)c * 2 + par) * 512 + wg * 32 + tid,
                               fb, __ATOMIC_RELAXED, __HIP_MEMORY_SCOPE_AGENT);
        }
      }
    }

    // ---- pollers: gather remote h[t] from OWN mailbox ----
    if (t + 1 < NUM_S && tid >= 256) {
      const int k = tid - 256;  // u64 chunk 0..255 (dims 2k,2k+1)
      if ((k >> 4) != wg) {     // own dims handled by leaders via LDS
        unsigned long long* p = reinterpret_cast<unsigned long long*>(
            mbox + ((size_t)wg * 2 + par) * 512) + k;
        unsigned long long v =
            __hip_atomic_load(p, __ATOMIC_ACQUIRE, __HIP_MEMORY_SCOPE_AGENT);
        int guard = 0;
        while (((unsigned)v == 0u || (unsigned)(v >> 32) == 0u) &&
               ++guard < (1 << 14))  // fail loud, never hang
          v = __hip_atomic_load(p, __ATOMIC_ACQUIRE, __HIP_MEMORY_SCOPE_AGENT);
        __hip_atomic_store(p, 0ULL, __ATOMIC_RELAXED, __HIP_MEMORY_SCOPE_AGENT);
        h_lds[nxt][2 * k]     = __uint_as_float((unsigned)v - 0x40000000u);
        h_lds[nxt][2 * k + 1] = __uint_as_float((unsigned)(v >> 32) - 0x40000000u);
      }
    }
    __syncthreads();  // bar 2: h[t] staged for everyone
  }
}

// ---------------------------------------------------------------------------
// Kernel D1: tag_space[s][c] = wout[s] . W_tag[c] + b_tag[c].
// ---------------------------------------------------------------------------
__global__ __launch_bounds__(256, 2) void tag_proj_kernel(
    const float* __restrict__ wout,   // [S][512]
    const float* __restrict__ W_tag,  // [64][512]
    const float* __restrict__ b_tag,  // [64]
    float* __restrict__ ts)           // [S][64]
{
  __shared__ __align__(16) float wl[4 * 512];
  const int wg = blockIdx.x, tid = threadIdx.x;
  const int s0 = wg * 4;
  {
    const float4* src = reinterpret_cast<const float4*>(wout + (size_t)s0 * 512);
    float4* dst = reinterpret_cast<float4*>(wl);
    dst[tid] = src[tid];
    dst[256 + tid] = src[256 + tid];
  }
  __syncthreads();
  const int c = tid & 63, q = tid >> 6;
  const float4* wt = reinterpret_cast<const float4*>(W_tag + (size_t)c * 512);
  const float4* hr = reinterpret_cast<const float4*>(wl + q * 512);
  float acc = b_tag[c];
#pragma unroll 8
  for (int j = 0; j < 128; ++j) {
    const float4 w = wt[j];
    const float4 h = hr[j];
    acc = fmaf(w.x, h.x, acc);
    acc = fmaf(w.y, h.y, acc);
    acc = fmaf(w.z, h.z, acc);
    acc = fmaf(w.w, h.w, acc);
  }
  ts[(size_t)(s0 + q) * 64 + c] = acc;
}

// ---------------------------------------------------------------------------
// Kernel D2: log_softmax over axis 0 (per tag column), f32 out.
// ---------------------------------------------------------------------------
__global__ __launch_bounds__(256, 1) void softmax_col_kernel(
    const float* __restrict__ ts,   // [S][64]
    float* __restrict__ out)        // [S][64] f32
{
  __shared__ float red[4];
  __shared__ float red2[4];
  const int c = blockIdx.x, tid = threadIdx.x;
  float m = -3.4e38f;
  for (int s = tid; s < NUM_S; s += 256) m = fmaxf(m, ts[(size_t)s * 64 + c]);
#pragma unroll
  for (int o = 32; o > 0; o >>= 1) m = fmaxf(m, __shfl_xor(m, o, 64));
  if ((tid & 63) == 0) red[tid >> 6] = m;
  __syncthreads();
  m = fmaxf(fmaxf(red[0], red[1]), fmaxf(red[2], red[3]));
  float sum = 0.0f;
  for (int s = tid; s < NUM_S; s += 256) sum += __expf(ts[(size_t)s * 64 + c] - m);
#pragma unroll
  for (int o = 32; o > 0; o >>= 1) sum += __shfl_xor(sum, o, 64);
  if ((tid & 63) == 0) red2[tid >> 6] = sum;
  __syncthreads();
  sum = red2[0] + red2[1] + red2[2] + red2[3];
  const float L = m + __logf(sum);
  for (int s = tid; s < NUM_S; s += 256)
    out[(size_t)s * 64 + c] = ts[(size_t)s * 64 + c] - L;
}

// ---------------------------------------------------------------------------
extern "C" void kernel_launch(void* const* d_in, const int* in_sizes, int n_in,
                              void* d_out, int out_size, void* d_ws, size_t ws_size,
                              hipStream_t stream) {
  (void)in_sizes; (void)n_in; (void)out_size; (void)ws_size;
  const int* word_idxs = (const int*)d_in[0];
  const int* char_idxs = (const int*)d_in[1];
  const int* char_lens = (const int*)d_in[2];
  const float* word_emb = (const float*)d_in[3];
  const float* char_emb = (const float*)d_in[4];
  const float* Wih_c = (const float*)d_in[5];
  const float* Whh_c = (const float*)d_in[6];
  const float* bih_c = (const float*)d_in[7];
  const float* bhh_c = (const float*)d_in[8];
  const float* Wih_w = (const float*)d_in[9];
  const float* Whh_w = (const float*)d_in[10];
  const float* bih_w = (const float*)d_in[11];
  const float* bhh_w = (const float*)d_in[12];
  const float* W_tag = (const float*)d_in[13];
  const float* b_tag = (const float*)d_in[14];

  char* ws = (char*)d_ws;
  float*    xpart  = (float*)(ws);                                   // 32 MB [4096][2048]
  float*    wout   = (float*)(ws + (size_t)32 * 1024 * 1024);        //  8 MB [4096][512]
  float*    cfeat  = (float*)(ws + (size_t)40 * 1024 * 1024);        //  2 MB [4096][128]
  float*    ts     = (float*)(ws + (size_t)42 * 1024 * 1024);        //  1 MB [4096][64]
  unsigned short* wih_bf = (unsigned short*)(ws + (size_t)43 * 1024 * 1024);  // 1.5 MB
  unsigned* mbox   = (unsigned*)(ws + (size_t)44 * 1024 * 1024 + 512 * 1024); // 64 KB

  hipMemsetAsync(mbox, 0, (size_t)16 * 2 * 512 * sizeof(unsigned), stream);
  cvt_bf16_kernel<<<384, 256, 0, stream>>>(Wih_w, wih_bf, (2048 * 384) / 8);
  char_lstm_kernel<<<256, 256, 0, stream>>>(char_idxs, char_lens, char_emb,
                                            Wih_c, Whh_c, bih_c, bhh_c, cfeat);
  word_input_kernel<<<64, 256, 0, stream>>>(word_idxs, word_emb, cfeat,
                                            wih_bf, bih_w, bhh_w, xpart);
  word_lstm_kernel<<<16, 512, 0, stream>>>(Whh_w, xpart, wout, mbox);
  tag_proj_kernel<<<1024, 256, 0, stream>>>(wout, W_tag, b_tag, ts);
  softmax_col_kernel<<<64, 256, 0, stream>>>(ts, (float*)d_out);
}

// Round 9
// 8572.794 us; speedup vs baseline: 1.5969x; 1.5969x over previous
//
#include <hip/hip_runtime.h>
#include <hip/hip_bf16.h>

// ---------------------------------------------------------------------------
// LSTMTagger: char-LSTM (batched, MFMA) -> word-LSTM (sequential, 16-WG
// tagged per-dim mailbox, 64B-padded lines, relaxed agent atomics) -> tag
// projection + log_softmax(axis=0). Float I/O f32; bf16 only in MFMA stages.
// Rules learned: sc0 hand-rolled BANNED (R3/R6); acquire-per-poll BANNED
// (R8); scattered per-leader store fans BANNED (R8); no intra-wave
// poller->waiter deps (R7). All spins guarded -> fail loud, never hang.
// ---------------------------------------------------------------------------

typedef short short8 __attribute__((ext_vector_type(8)));   // 8 bf16 (4 VGPRs)
typedef float f32x4 __attribute__((ext_vector_type(4)));    // MFMA acc

#define NUM_S 4096
#define NUM_L 16

__device__ __forceinline__ unsigned short f2bf(float f) {  // RTNE
  unsigned x = __float_as_uint(f);
  x += 0x7FFFu + ((x >> 16) & 1u);
  return (unsigned short)(x >> 16);
}
__device__ __forceinline__ uint4 packf8(float4 a, float4 b) {  // 8 f32 -> 8 bf16
  uint4 r;
  r.x = (unsigned)f2bf(a.x) | ((unsigned)f2bf(a.y) << 16);
  r.y = (unsigned)f2bf(a.z) | ((unsigned)f2bf(a.w) << 16);
  r.z = (unsigned)f2bf(b.x) | ((unsigned)f2bf(b.y) << 16);
  r.w = (unsigned)f2bf(b.z) | ((unsigned)f2bf(b.w) << 16);
  return r;
}
__device__ __forceinline__ short8 pack_bf8(const float* src) {  // 16B-aligned
  const float4 a = *reinterpret_cast<const float4*>(src);
  const float4 b = *reinterpret_cast<const float4*>(src + 4);
  uint4 u = packf8(a, b);
  union { uint4 u; short8 s; } cv; cv.u = u;
  return cv.s;
}
__device__ __forceinline__ float sigm(float x) { return 1.0f / (1.0f + __expf(-x)); }
__device__ __forceinline__ float tanh_f(float x) {
  x = fminf(15.0f, fmaxf(-15.0f, x));
  float e = __expf(2.0f * x);
  return (e - 1.0f) / (e + 1.0f);
}

// ---------------------------------------------------------------------------
// Kernel A: char LSTM. One WG = 16 words, 256 threads (4 waves).
// Weights (Wih_c||Whh_c as 512x256) held as bf16 MFMA B-frags in VGPRs.
// ---------------------------------------------------------------------------
__global__ __launch_bounds__(256, 1) void char_lstm_kernel(
    const int* __restrict__ char_idxs,    // [S][L]
    const int* __restrict__ char_lens,    // [S]
    const float* __restrict__ char_emb,   // [128][128]
    const float* __restrict__ Wih_c,      // [512][128]
    const float* __restrict__ Whh_c,      // [512][128]
    const float* __restrict__ bih_c,      // [512]
    const float* __restrict__ bhh_c,      // [512]
    float* __restrict__ char_feat)        // [S][128]
{
  constexpr int XSTR = 264;  // 256 + 8 pad (bf16 elems)
  __shared__ __align__(16) unsigned short X[16 * XSTR];

  const int wg = blockIdx.x;
  const int tid = threadIdx.x;
  const int lane = tid & 63;
  const int wv = tid >> 6;
  const int col = lane & 15;
  const int krow = lane >> 4;

  short8 wfrag[8][8];
#pragma unroll
  for (int p = 0; p < 8; ++p) {
    const int nt = (p >> 1) * 8 + 2 * wv + (p & 1);
    const int n = nt * 16 + col;
#pragma unroll
    for (int kt = 0; kt < 8; ++kt) {
      const int k = kt * 32 + krow * 8;
      const float* src = (kt < 4) ? (Wih_c + n * 128 + k)
                                  : (Whh_c + n * 128 + (k - 128));
      wfrag[p][kt] = pack_bf8(src);
    }
  }
  float bsum[8];
#pragma unroll
  for (int p = 0; p < 8; ++p) {
    const int nt = (p >> 1) * 8 + 2 * wv + (p & 1);
    const int n = nt * 16 + col;
    bsum[p] = bih_c[n] + bhh_c[n];
  }
  int clen[4];
#pragma unroll
  for (int r = 0; r < 4; ++r) clen[r] = char_lens[wg * 16 + krow * 4 + r];

  {
    const int m = tid >> 4, c = tid & 15;
    uint4 z; z.x = z.y = z.z = z.w = 0u;
    *reinterpret_cast<uint4*>(&X[m * XSTR + 128 + c * 8]) = z;
  }
  float cstate[8];
#pragma unroll
  for (int i = 0; i < 8; ++i) cstate[i] = 0.0f;

  for (int l = 0; l < NUM_L; ++l) {
    {
      const int m = tid >> 4, c = tid & 15;
      const int ci = char_idxs[(wg * 16 + m) * NUM_L + l];
      const float4 a = *reinterpret_cast<const float4*>(char_emb + ci * 128 + c * 8);
      const float4 b = *reinterpret_cast<const float4*>(char_emb + ci * 128 + c * 8 + 4);
      *reinterpret_cast<uint4*>(&X[m * XSTR + c * 8]) = packf8(a, b);
    }
    __syncthreads();

    short8 afr[8];
#pragma unroll
    for (int kt = 0; kt < 8; ++kt)
      afr[kt] = *reinterpret_cast<const short8*>(&X[col * XSTR + kt * 32 + krow * 8]);

    f32x4 acc[8];
#pragma unroll
    for (int p = 0; p < 8; ++p) { f32x4 v = {bsum[p], bsum[p], bsum[p], bsum[p]}; acc[p] = v; }
#pragma unroll
    for (int kt = 0; kt < 8; ++kt)
#pragma unroll
      for (int p = 0; p < 8; ++p)
        acc[p] = __builtin_amdgcn_mfma_f32_16x16x32_bf16(afr[kt], wfrag[p][kt], acc[p], 0, 0, 0);
    __syncthreads();

#pragma unroll
    for (int sub = 0; sub < 2; ++sub) {
#pragma unroll
      for (int r = 0; r < 4; ++r) {
        const int m = krow * 4 + r;
        const int d = (2 * wv + sub) * 16 + col;
        const float iv = acc[0 + sub][r];
        const float fv = acc[2 + sub][r];
        const float gv = acc[4 + sub][r];
        const float ov = acc[6 + sub][r];
        const float cc = sigm(fv) * cstate[sub * 4 + r] + sigm(iv) * tanh_f(gv);
        const float hh = sigm(ov) * tanh_f(cc);
        cstate[sub * 4 + r] = cc;
        X[m * XSTR + 128 + d] = (unsigned short)f2bf(hh);
        if (clen[r] == l + 1) char_feat[(wg * 16 + m) * 128 + d] = hh;
      }
    }
  }
}

// ---------------------------------------------------------------------------
// Kernel W: convert Wih_w f32 -> bf16 workspace.
// ---------------------------------------------------------------------------
__global__ __launch_bounds__(256) void cvt_bf16_kernel(
    const float* __restrict__ in, unsigned short* __restrict__ out, int n8) {
  const int i = blockIdx.x * 256 + threadIdx.x;
  if (i < n8) {
    const float4 a = reinterpret_cast<const float4*>(in)[2 * i];
    const float4 b = reinterpret_cast<const float4*>(in)[2 * i + 1];
    reinterpret_cast<uint4*>(out)[i] = packf8(a, b);
  }
}

// ---------------------------------------------------------------------------
// Kernel B: xpart[t] = Wih_w @ [we[t] | char_feat[t]] + bih_w + bhh_w.
// ---------------------------------------------------------------------------
__global__ __launch_bounds__(256, 1) void word_input_kernel(
    const int* __restrict__ word_idxs,
    const float* __restrict__ word_emb,            // [V][256]
    const float* __restrict__ char_feat,           // [S][128]
    const unsigned short* __restrict__ wih_bf,     // [2048][384] bf16
    const float* __restrict__ bih_w,               // [2048]
    const float* __restrict__ bhh_w,               // [2048]
    float* __restrict__ xpart)                     // [S][2048]
{
  constexpr int XSTR = 392;  // 384 + 8 pad (bf16)
  __shared__ __align__(16) unsigned short X[64 * XSTR];
  const int wg = blockIdx.x, tid = threadIdx.x;
  const int lane = tid & 63, wv = tid >> 6, col = lane & 15, krow = lane >> 4;
  const int t0 = wg * 64;

#pragma unroll
  for (int rr = 0; rr < 4; ++rr) {
    const int m = rr * 16 + (tid >> 4), c = tid & 15;
    const int widx = word_idxs[t0 + m];
    const float* we = word_emb + (size_t)widx * 256;
    const float4 a0 = *reinterpret_cast<const float4*>(we + c * 8);
    const float4 b0 = *reinterpret_cast<const float4*>(we + c * 8 + 4);
    *reinterpret_cast<uint4*>(&X[m * XSTR + c * 8]) = packf8(a0, b0);
    const float4 a1 = *reinterpret_cast<const float4*>(we + 128 + c * 8);
    const float4 b1 = *reinterpret_cast<const float4*>(we + 128 + c * 8 + 4);
    *reinterpret_cast<uint4*>(&X[m * XSTR + 128 + c * 8]) = packf8(a1, b1);
    const float* cf = char_feat + (size_t)(t0 + m) * 128;
    const float4 a2 = *reinterpret_cast<const float4*>(cf + c * 8);
    const float4 b2 = *reinterpret_cast<const float4*>(cf + c * 8 + 4);
    *reinterpret_cast<uint4*>(&X[m * XSTR + 256 + c * 8]) = packf8(a2, b2);
  }
  __syncthreads();

  short8 afr[4][12];
#pragma unroll
  for (int mt = 0; mt < 4; ++mt)
#pragma unroll
    for (int kt = 0; kt < 12; ++kt)
      afr[mt][kt] = *reinterpret_cast<const short8*>(
          &X[(mt * 16 + col) * XSTR + kt * 32 + krow * 8]);

  for (int nn = 0; nn < 32; ++nn) {
    const int nt = wv * 32 + nn;
    const int n = nt * 16 + col;
    const float bs = bih_w[n] + bhh_w[n];
    f32x4 acc[4];
#pragma unroll
    for (int mt = 0; mt < 4; ++mt) { f32x4 v = {bs, bs, bs, bs}; acc[mt] = v; }
#pragma unroll
    for (int kt = 0; kt < 12; ++kt) {
      const short8 bfr = *reinterpret_cast<const short8*>(
          wih_bf + (size_t)n * 384 + kt * 32 + krow * 8);
#pragma unroll
      for (int mt = 0; mt < 4; ++mt)
        acc[mt] = __builtin_amdgcn_mfma_f32_16x16x32_bf16(afr[mt][kt], bfr, acc[mt], 0, 0, 0);
    }
#pragma unroll
    for (int mt = 0; mt < 4; ++mt)
#pragma unroll
      for (int r = 0; r < 4; ++r)
        xpart[(size_t)(t0 + mt * 16 + krow * 4 + r) * 2048 + n] = acc[mt][r];
  }
}

// ---------------------------------------------------------------------------
// Kernel C: sequential word LSTM. 16 WGs x 512 thr, R5 skeleton + tagged
// per-dim 64B-padded mailbox. tid = dim(5b)|gate(2b)|seg(2b); quarter-row
// of Whh in VGPRs (seg-rotated -> conflict-free LDS h reads). Per step:
//   A) FMA + shfl seg-reduce; seg0 adds xpart, writes glds. bar1.
//   B) leaders (tid<32): nonlinearity (c in reg); wout store; own dim to
//      h_lds[nxt]; ONE relaxed agent u64 store {tag=t+1 | bits(h)} to
//      hxp[dim*8] (64B stride: each dim owns a cache line; 32 lanes store
//      in one instruction, parallel MALL slices).
//   C) all threads: d = tid; skip own WG's dims; relaxed-poll u64 at
//      hxp[d*8] until tag==t+1 (<=15 spinning pollers per line, the
//      theoretical floor); h_lds[nxt][d] = payload. bar2.
// Exact tags: no zero-flags, no clears, no ring hazards, replay-safe
// (memset once per launch). Guards 2^12 -> fail loud, never hang.
// ---------------------------------------------------------------------------
__global__ __launch_bounds__(512, 1) void word_lstm_kernel(
    const float* __restrict__ Whh_w,        // [2048][512] f32
    const float* __restrict__ xpart,        // [S][2048]
    float* __restrict__ wout,               // [S][512] plain f32
    unsigned long long* __restrict__ hxp)   // [512*8] u64, dim d at d*8
{
  const int tid = threadIdx.x;
  const int wg = blockIdx.x;           // 16 WGs
  const int dim = tid >> 4;            // 0..31
  const int gate = (tid >> 2) & 3;     // i,f,g,o
  const int seg = tid & 3;             // K quarter
  const int R = gate * 512 + wg * 32 + dim;

  // quarter-row of Whh, pre-rotated by seg (compile-time reg indices; LDS
  // chunk order differs per seg -> no 4-way bank conflict on h reads)
  float4 w4[32];
  {
    const float4* wrow = reinterpret_cast<const float4*>(
        Whh_w + (size_t)R * 512 + seg * 128);
#pragma unroll
    for (int i = 0; i < 32; ++i) w4[i] = wrow[(i + seg) & 31];
  }

  __shared__ __align__(16) float h_lds[2][512];
  __shared__ float glds[128];
  h_lds[0][tid] = 0.0f;
  float creg = 0.0f;
  float xp = (seg == 0) ? xpart[R] : 0.0f;  // t=0 prefetch
  __syncthreads();

  for (int t = 0; t < NUM_S; ++t) {
    const int cur = t & 1, nxt = cur ^ 1;

    // ---- phase A: gates = Whh @ h (2-way split chains) ----
    const float4* h4 = reinterpret_cast<const float4*>(&h_lds[cur][0]) + seg * 32;
    float a0 = 0.0f, a1 = 0.0f;
#pragma unroll
    for (int jj = 0; jj < 32; jj += 2) {
      const int j0 = (jj + seg) & 31;
      const int j1 = (jj + 1 + seg) & 31;
      const float4 hA = h4[j0]; const float4 wA = w4[jj];
      const float4 hB = h4[j1]; const float4 wB = w4[jj + 1];
      a0 = fmaf(wA.x, hA.x, a0); a0 = fmaf(wA.y, hA.y, a0);
      a0 = fmaf(wA.z, hA.z, a0); a0 = fmaf(wA.w, hA.w, a0);
      a1 = fmaf(wB.x, hB.x, a1); a1 = fmaf(wB.y, hB.y, a1);
      a1 = fmaf(wB.z, hB.z, a1); a1 = fmaf(wB.w, hB.w, a1);
    }
    float acc = a0 + a1;
    acc += __shfl_xor(acc, 1, 64);
    acc += __shfl_xor(acc, 2, 64);
    if (seg == 0) {
      glds[gate * 32 + dim] = acc + xp;
      if (t + 1 < NUM_S) xp = xpart[(size_t)(t + 1) * 2048 + R];  // prefetch
    }
    __syncthreads();  // bar 1: gates visible

    // ---- phase B: leaders nonlinearity + tagged mailbox store ----
    if (tid < 32) {
      const float iv = glds[tid];
      const float fv = glds[32 + tid];
      const float gv = glds[64 + tid];
      const float ov = glds[96 + tid];
      const float cc = sigm(fv) * creg + sigm(iv) * tanh_f(gv);
      const float hh = sigm(ov) * tanh_f(cc);
      creg = cc;
      wout[(size_t)t * 512 + wg * 32 + tid] = hh;
      h_lds[nxt][wg * 32 + tid] = hh;  // own dims: LDS, no round-trip
      if (t + 1 < NUM_S) {
        const unsigned long long pv =
            ((unsigned long long)(unsigned)(t + 1) << 32) |
            (unsigned long long)__float_as_uint(hh);
        __hip_atomic_store(hxp + (size_t)(wg * 32 + tid) * 8, pv,
                           __ATOMIC_RELAXED, __HIP_MEMORY_SCOPE_AGENT);
      }
    }

    // ---- phase C: per-dim tagged poll (relaxed; <=15 pollers/line) ----
    if (t + 1 < NUM_S) {
      const int d = tid;
      if ((d >> 5) != wg) {
        const unsigned long long* p = hxp + (size_t)d * 8;
        unsigned long long v =
            __hip_atomic_load(p, __ATOMIC_RELAXED, __HIP_MEMORY_SCOPE_AGENT);
        int guard = 0;
        while ((unsigned)(v >> 32) != (unsigned)(t + 1) &&
               ++guard < (1 << 12))  // fail loud, never hang
          v = __hip_atomic_load(p, __ATOMIC_RELAXED, __HIP_MEMORY_SCOPE_AGENT);
        h_lds[nxt][d] = __uint_as_float((unsigned)v);
      }
    }
    __syncthreads();  // bar 2: h[t] staged for everyone
  }
}

// ---------------------------------------------------------------------------
// Kernel D1: tag_space[s][c] = wout[s] . W_tag[c] + b_tag[c].
// ---------------------------------------------------------------------------
__global__ __launch_bounds__(256, 2) void tag_proj_kernel(
    const float* __restrict__ wout,   // [S][512]
    const float* __restrict__ W_tag,  // [64][512]
    const float* __restrict__ b_tag,  // [64]
    float* __restrict__ ts)           // [S][64]
{
  __shared__ __align__(16) float wl[4 * 512];
  const int wg = blockIdx.x, tid = threadIdx.x;
  const int s0 = wg * 4;
  {
    const float4* src = reinterpret_cast<const float4*>(wout + (size_t)s0 * 512);
    float4* dst = reinterpret_cast<float4*>(wl);
    dst[tid] = src[tid];
    dst[256 + tid] = src[256 + tid];
  }
  __syncthreads();
  const int c = tid & 63, q = tid >> 6;
  const float4* wt = reinterpret_cast<const float4*>(W_tag + (size_t)c * 512);
  const float4* hr = reinterpret_cast<const float4*>(wl + q * 512);
  float acc = b_tag[c];
#pragma unroll 8
  for (int j = 0; j < 128; ++j) {
    const float4 w = wt[j];
    const float4 h = hr[j];
    acc = fmaf(w.x, h.x, acc);
    acc = fmaf(w.y, h.y, acc);
    acc = fmaf(w.z, h.z, acc);
    acc = fmaf(w.w, h.w, acc);
  }
  ts[(size_t)(s0 + q) * 64 + c] = acc;
}

// ---------------------------------------------------------------------------
// Kernel D2: log_softmax over axis 0 (per tag column), f32 out.
// ---------------------------------------------------------------------------
__global__ __launch_bounds__(256, 1) void softmax_col_kernel(
    const float* __restrict__ ts,   // [S][64]
    float* __restrict__ out)        // [S][64] f32
{
  __shared__ float red[4];
  __shared__ float red2[4];
  const int c = blockIdx.x, tid = threadIdx.x;
  float m = -3.4e38f;
  for (int s = tid; s < NUM_S; s += 256) m = fmaxf(m, ts[(size_t)s * 64 + c]);
#pragma unroll
  for (int o = 32; o > 0; o >>= 1) m = fmaxf(m, __shfl_xor(m, o, 64));
  if ((tid & 63) == 0) red[tid >> 6] = m;
  __syncthreads();
  m = fmaxf(fmaxf(red[0], red[1]), fmaxf(red[2], red[3]));
  float sum = 0.0f;
  for (int s = tid; s < NUM_S; s += 256) sum += __expf(ts[(size_t)s * 64 + c] - m);
#pragma unroll
  for (int o = 32; o > 0; o >>= 1) sum += __shfl_xor(sum, o, 64);
  if ((tid & 63) == 0) red2[tid >> 6] = sum;
  __syncthreads();
  sum = red2[0] + red2[1] + red2[2] + red2[3];
  const float L = m + __logf(sum);
  for (int s = tid; s < NUM_S; s += 256)
    out[(size_t)s * 64 + c] = ts[(size_t)s * 64 + c] - L;
}

// ---------------------------------------------------------------------------
extern "C" void kernel_launch(void* const* d_in, const int* in_sizes, int n_in,
                              void* d_out, int out_size, void* d_ws, size_t ws_size,
                              hipStream_t stream) {
  (void)in_sizes; (void)n_in; (void)out_size; (void)ws_size;
  const int* word_idxs = (const int*)d_in[0];
  const int* char_idxs = (const int*)d_in[1];
  const int* char_lens = (const int*)d_in[2];
  const float* word_emb = (const float*)d_in[3];
  const float* char_emb = (const float*)d_in[4];
  const float* Wih_c = (const float*)d_in[5];
  const float* Whh_c = (const float*)d_in[6];
  const float* bih_c = (const float*)d_in[7];
  const float* bhh_c = (const float*)d_in[8];
  const float* Wih_w = (const float*)d_in[9];
  const float* Whh_w = (const float*)d_in[10];
  const float* bih_w = (const float*)d_in[11];
  const float* bhh_w = (const float*)d_in[12];
  const float* W_tag = (const float*)d_in[13];
  const float* b_tag = (const float*)d_in[14];

  char* ws = (char*)d_ws;
  float*    xpart  = (float*)(ws);                                   // 32 MB [4096][2048]
  float*    wout   = (float*)(ws + (size_t)32 * 1024 * 1024);        //  8 MB [4096][512]
  float*    cfeat  = (float*)(ws + (size_t)40 * 1024 * 1024);        //  2 MB [4096][128]
  float*    ts     = (float*)(ws + (size_t)42 * 1024 * 1024);        //  1 MB [4096][64]
  unsigned short* wih_bf = (unsigned short*)(ws + (size_t)43 * 1024 * 1024);  // 1.5 MB
  unsigned long long* hxp =
      (unsigned long long*)(ws + (size_t)44 * 1024 * 1024 + 512 * 1024);      // 32 KB

  hipMemsetAsync(hxp, 0, (size_t)512 * 8 * sizeof(unsigned long long), stream);
  cvt_bf16_kernel<<<384, 256, 0, stream>>>(Wih_w, wih_bf, (2048 * 384) / 8);
  char_lstm_kernel<<<256, 256, 0, stream>>>(char_idxs, char_lens, char_emb,
                                            Wih_c, Whh_c, bih_c, bhh_c, cfeat);
  word_input_kernel<<<64, 256, 0, stream>>>(word_idxs, word_emb, cfeat,
                                            wih_bf, bih_w, bhh_w, xpart);
  word_lstm_kernel<<<16, 512, 0, stream>>>(Whh_w, xpart, wout, hxp);
  tag_proj_kernel<<<1024, 256, 0, stream>>>(wout, W_tag, b_tag, ts);
  softmax_col_kernel<<<64, 256, 0, stream>>>(ts, (float*)d_out);
}